// Round 3
// baseline (985.604 us; speedup 1.0000x reference)
//
#include <hip/hip_runtime.h>
#include <math.h>

#define BSZ 2
#define SEQ 2048
#define DIM 2048
#define NH 32
#define NKV 8
#define HD 64
#define KVDIM 512

typedef short short8 __attribute__((ext_vector_type(8)));
typedef short short4v __attribute__((ext_vector_type(4)));
typedef float f32x4 __attribute__((ext_vector_type(4)));

__device__ __forceinline__ short fbf(float x) {
    unsigned u = __float_as_uint(x);
    u = (u + 0x7fffu + ((u >> 16) & 1u)) >> 16;   // RNE f32->bf16
    return (short)u;
}

#define AS1(p) ((const __attribute__((address_space(1))) void*)(p))
#define AS3(p) ((__attribute__((address_space(3))) void*)(p))

// ---------------------------------------------------------------------------
// fp32 -> bf16 convert
// ---------------------------------------------------------------------------
__global__ __launch_bounds__(256) void f2bf(const float* __restrict__ in,
                                            short* __restrict__ out, int n4) {
    int i = blockIdx.x * 256 + threadIdx.x;
    if (i >= n4) return;
    float4 f = ((const float4*)in)[i];
    short4v s = { fbf(f.x), fbf(f.y), fbf(f.z), fbf(f.w) };
    ((short4v*)out)[i] = s;
}

// ---------------------------------------------------------------------------
// bf16 NT GEMM, m97-style: global_load_lds width-16 staging, BK=64,
// unpadded [row][64] bf16 LDS rows with XOR chunk swizzle (swizzle applied on
// the fetch side since global_load_lds places data at lane*16).
// 128x128 tile, 4 waves, each 64x64 via 4x4 MFMA 16x16x32.
// ---------------------------------------------------------------------------
__global__ __launch_bounds__(256) void gemm_bf16(const short* __restrict__ A,
                                                 const short* __restrict__ W,
                                                 float* __restrict__ C,
                                                 int M, int N, int K) {
    __shared__ short As[128 * 64];
    __shared__ short Bs[128 * 64];
    const int tid = threadIdx.x;
    const int lane = tid & 63, wave = tid >> 6;
    const int l15 = lane & 15, quad = lane >> 4;
    const int m0 = blockIdx.y * 128, n0 = blockIdx.x * 128;
    const int wm = (wave >> 1) * 64, wn = (wave & 1) * 64;
    f32x4 acc[4][4] = {};
    int srow[4], gcol[4];
#pragma unroll
    for (int v = 0; v < 4; ++v) {
        int s = v * 256 + tid;
        srow[v] = s >> 3;
        gcol[v] = ((s & 7) ^ (srow[v] & 7)) * 8;   // LDS slot s&7 holds this global chunk
    }
    for (int kb = 0; kb < K; kb += 64) {
        __syncthreads();
#pragma unroll
        for (int v = 0; v < 4; ++v) {
            int s = v * 256 + tid;
            __builtin_amdgcn_global_load_lds(AS1(A + (size_t)(m0 + srow[v]) * K + kb + gcol[v]),
                                             AS3(&As[s * 8]), 16, 0, 0);
            __builtin_amdgcn_global_load_lds(AS1(W + (size_t)(n0 + srow[v]) * K + kb + gcol[v]),
                                             AS3(&Bs[s * 8]), 16, 0, 0);
        }
        __syncthreads();
#pragma unroll
        for (int kh = 0; kh < 2; ++kh) {
            const int cs = ((kh * 4 + quad) ^ (l15 & 7)) * 8;
            short8 af[4], bf8[4];
#pragma unroll
            for (int i = 0; i < 4; ++i)
                af[i] = *(const short8*)&As[(wm + i * 16 + l15) * 64 + cs];
#pragma unroll
            for (int j = 0; j < 4; ++j)
                bf8[j] = *(const short8*)&Bs[(wn + j * 16 + l15) * 64 + cs];
#pragma unroll
            for (int i = 0; i < 4; ++i)
#pragma unroll
                for (int j = 0; j < 4; ++j)
                    acc[i][j] = __builtin_amdgcn_mfma_f32_16x16x32_bf16(af[i], bf8[j], acc[i][j], 0, 0, 0);
        }
    }
#pragma unroll
    for (int i = 0; i < 4; ++i)
#pragma unroll
        for (int j = 0; j < 4; ++j)
#pragma unroll
            for (int r = 0; r < 4; ++r)
                C[(size_t)(m0 + wm + i * 16 + quad * 4 + r) * N + n0 + wn + j * 16 + l15] = acc[i][j][r];
}

// ---------------------------------------------------------------------------
// Fused RoPE + scale + fp32->bf16. X: [B,S,heads,HD] fp32 -> Y same layout bf16
// ---------------------------------------------------------------------------
__global__ __launch_bounds__(256) void rope_bf16(const float* __restrict__ X,
                                                 short* __restrict__ Y,
                                                 const float* __restrict__ cosT,
                                                 const float* __restrict__ sinT,
                                                 int heads, float scale, int total) {
    int i = blockIdx.x * 256 + threadIdx.x;
    if (i >= total) return;
    int d0 = (i & 7) * 4;
    int rh = i >> 3;
    int s = (rh / heads) & (SEQ - 1);
    const float* base = X + (size_t)rh * HD;
    float4 x1 = *(const float4*)(base + d0);
    float4 x2 = *(const float4*)(base + d0 + 32);
    float4 c1 = *(const float4*)(cosT + s * HD + d0);
    float4 s1 = *(const float4*)(sinT + s * HD + d0);
    float4 c2 = *(const float4*)(cosT + s * HD + d0 + 32);
    float4 s2 = *(const float4*)(sinT + s * HD + d0 + 32);
    short4v o1 = { fbf((x1.x * c1.x - x2.x * s1.x) * scale),
                   fbf((x1.y * c1.y - x2.y * s1.y) * scale),
                   fbf((x1.z * c1.z - x2.z * s1.z) * scale),
                   fbf((x1.w * c1.w - x2.w * s1.w) * scale) };
    short4v o2 = { fbf((x2.x * c2.x + x1.x * s2.x) * scale),
                   fbf((x2.y * c2.y + x1.y * s2.y) * scale),
                   fbf((x2.z * c2.z + x1.z * s2.z) * scale),
                   fbf((x2.w * c2.w + x1.w * s2.w) * scale) };
    *(short4v*)(Y + (size_t)rh * HD + d0) = o1;
    *(short4v*)(Y + (size_t)rh * HD + d0 + 32) = o2;
}

// ---------------------------------------------------------------------------
// V transpose: Vf [B,S,NKV,HD] fp32 -> VT [B,NKV,HD,SEQ] bf16.
// grid (SEQ/64, B*NKV), 64x64 tile via LDS.
// ---------------------------------------------------------------------------
__global__ __launch_bounds__(256) void transv(const float* __restrict__ Vf,
                                              short* __restrict__ VT) {
    __shared__ float T[64][65];
    const int tid = threadIdx.x;
    const int s0 = blockIdx.x * 64;
    const int bk = blockIdx.y;                 // b*NKV + kvh
    const float* src = Vf + ((size_t)(bk >> 3) * SEQ + s0) * KVDIM + (bk & 7) * HD;
#pragma unroll
    for (int v = 0; v < 4; ++v) {
        int srow = (tid >> 4) + v * 16;
        int d4 = (tid & 15) * 4;
        float4 f = *(const float4*)(src + (size_t)srow * KVDIM + d4);
        T[srow][d4 + 0] = f.x; T[srow][d4 + 1] = f.y;
        T[srow][d4 + 2] = f.z; T[srow][d4 + 3] = f.w;
    }
    __syncthreads();
    const int d = tid >> 2, sg = tid & 3;
#pragma unroll
    for (int j = 0; j < 4; ++j) {
        int ss = sg * 16 + j * 4;
        short4v o = { fbf(T[ss + 0][d]), fbf(T[ss + 1][d]),
                      fbf(T[ss + 2][d]), fbf(T[ss + 3][d]) };
        *(short4v*)(VT + ((size_t)bk * HD + d) * SEQ + s0 + ss) = o;
    }
}

// ---------------------------------------------------------------------------
// Flash attention v2: no LDS, no barriers. Per wave: 16 q-rows.
// S^T = K*Q^T (q-row on l15) -> in-register exp2 softmax (stats are per-lane
// scalars, 2 shuffles) -> O = P*V with a k-permuted contraction so P's
// C-layout feeds the A-operand directly (no cross-lane transform):
//   k-pos (quad,j) of MFMA-half hh  <->  kk = 32*hh + 16*(j>>2) + 4*quad + (j&3)
// V B-frags load the matching kk order from VT as 2x8B per half.
// ---------------------------------------------------------------------------
__global__ __launch_bounds__(256, 3) void flash2(const short* __restrict__ Qb,
                                                 const short* __restrict__ Kb,
                                                 const short* __restrict__ VT,
                                                 short* __restrict__ O) {
    const int qt = blockIdx.x, bh = blockIdx.y;
    const int b = bh >> 5, h = bh & 31, kvh = h >> 2;
    const int tid = threadIdx.x;
    const int wave = tid >> 6, lane = tid & 63;
    const int l15 = lane & 15, quad = lane >> 4;

    const short* Qh = Qb + ((size_t)b * SEQ + qt * 64 + wave * 16 + l15) * DIM + h * HD + quad * 8;
    short8 qf0 = *(const short8*)Qh;
    short8 qf1 = *(const short8*)(Qh + 32);

    const short* Kh = Kb + (size_t)b * SEQ * KVDIM + kvh * HD + quad * 8;
    const short* Vh = VT + (size_t)(b * NKV + kvh) * HD * SEQ + (size_t)l15 * SEQ + quad * 4;

    f32x4 o[4] = {};
    float m = -1e30f, l = 0.f;

    for (int kt = 0; kt <= qt; ++kt) {
        // K A-frags: direct 16B global loads (L2-resident tile)
        const short* kp = Kh + (size_t)(kt * 64 + l15) * KVDIM;
        short8 kf0[4], kf1[4];
#pragma unroll
        for (int nt = 0; nt < 4; ++nt) {
            kf0[nt] = *(const short8*)(kp + (size_t)nt * 16 * KVDIM);
            kf1[nt] = *(const short8*)(kp + (size_t)nt * 16 * KVDIM + 32);
        }
        f32x4 st[4] = {};
#pragma unroll
        for (int nt = 0; nt < 4; ++nt) {
            st[nt] = __builtin_amdgcn_mfma_f32_16x16x32_bf16(kf0[nt], qf0, st[nt], 0, 0, 0);
            st[nt] = __builtin_amdgcn_mfma_f32_16x16x32_bf16(kf1[nt], qf1, st[nt], 0, 0, 0);
        }
        // V B-frags issued early to hide latency through softmax
        const short* vp = Vh + kt * 64;
        short8 vf[4][2];
#pragma unroll
        for (int dt = 0; dt < 4; ++dt)
#pragma unroll
            for (int hh = 0; hh < 2; ++hh) {
                short4v v0 = *(const short4v*)(vp + (size_t)dt * 16 * SEQ + hh * 32);
                short4v v1 = *(const short4v*)(vp + (size_t)dt * 16 * SEQ + hh * 32 + 16);
                short8 t;
                t[0] = v0[0]; t[1] = v0[1]; t[2] = v0[2]; t[3] = v0[3];
                t[4] = v1[0]; t[5] = v1[1]; t[6] = v1[2]; t[7] = v1[3];
                vf[dt][hh] = t;
            }
        if (kt == qt) {           // causal mask, diagonal tile only
            const int qloc = wave * 16 + l15;
#pragma unroll
            for (int nt = 0; nt < 4; ++nt)
#pragma unroll
                for (int r = 0; r < 4; ++r)
                    if (nt * 16 + quad * 4 + r > qloc) st[nt][r] = -1e30f;
        }
        // online softmax (exp2 domain); row stats per lane, reduce over quads
        float mx = st[0][0];
#pragma unroll
        for (int nt = 0; nt < 4; ++nt)
#pragma unroll
            for (int r = 0; r < 4; ++r) mx = fmaxf(mx, st[nt][r]);
        mx = fmaxf(mx, __shfl_xor(mx, 16));
        mx = fmaxf(mx, __shfl_xor(mx, 32));
        float mn = fmaxf(m, mx);
        float al = exp2f(m - mn);
        m = mn;
        float p[4][4];
        float rs = 0.f;
#pragma unroll
        for (int nt = 0; nt < 4; ++nt)
#pragma unroll
            for (int r = 0; r < 4; ++r) {
                p[nt][r] = exp2f(st[nt][r] - mn);
                rs += p[nt][r];
            }
        rs += __shfl_xor(rs, 16);
        rs += __shfl_xor(rs, 32);
        l = l * al + rs;
        // P -> A-frags via the k-permutation (pure pack, no shuffles)
        short8 af0, af1;
#pragma unroll
        for (int r = 0; r < 4; ++r) {
            af0[r] = fbf(p[0][r]); af0[r + 4] = fbf(p[1][r]);
            af1[r] = fbf(p[2][r]); af1[r + 4] = fbf(p[3][r]);
        }
        float alr[4];
#pragma unroll
        for (int r = 0; r < 4; ++r) alr[r] = __shfl(al, quad * 4 + r);
#pragma unroll
        for (int dt = 0; dt < 4; ++dt) {
            f32x4 t = o[dt];
            t[0] *= alr[0]; t[1] *= alr[1]; t[2] *= alr[2]; t[3] *= alr[3];
            t = __builtin_amdgcn_mfma_f32_16x16x32_bf16(af0, vf[dt][0], t, 0, 0, 0);
            t = __builtin_amdgcn_mfma_f32_16x16x32_bf16(af1, vf[dt][1], t, 0, 0, 0);
            o[dt] = t;
        }
    }
    float lr[4];
#pragma unroll
    for (int r = 0; r < 4; ++r) lr[r] = 1.0f / __shfl(l, quad * 4 + r);
    short* Oo = O + ((size_t)b * SEQ + qt * 64 + wave * 16 + quad * 4) * DIM + h * HD + l15;
#pragma unroll
    for (int r = 0; r < 4; ++r)
#pragma unroll
        for (int dt = 0; dt < 4; ++dt)
            Oo[(size_t)r * DIM + dt * 16] = fbf(o[dt][r] * lr[r]);
}

// ---------------------------------------------------------------------------
extern "C" void kernel_launch(void* const* d_in, const int* in_sizes, int n_in,
                              void* d_out, int out_size, void* d_ws, size_t ws_size,
                              hipStream_t stream) {
    const float* X    = (const float*)d_in[0];
    const float* cosT = (const float*)d_in[2];
    const float* sinT = (const float*)d_in[3];
    const float* Wq   = (const float*)d_in[4];
    const float* Wk   = (const float*)d_in[5];
    const float* Wv   = (const float*)d_in[6];
    const float* Wo   = (const float*)d_in[7];

    char* ws = (char*)d_ws;
    float* Kf   = (float*)(ws);                    // 8.4 MB fp32 K pre-rope
    float* Vf   = (float*)(ws + 8388608);          // 8.4 MB fp32 V
    short* Xb   = (short*)(ws + 16777216);         // 16.8 MB bf16 X; Qb aliases after X dead
    short* Qbb  = Xb;
    short* ATTb = (short*)(ws + 33554432);         // 16.8 MB bf16 attn out
    short* Wqob = (short*)(ws + 50331648);         // 8.4 MB bf16 Wq, later Wo
    short* VTb  = (short*)(ws + 50331648);         // alias: live only between gemmQ and flash
    short* Wkb  = (short*)(ws + 58720256);         // 2.1 MB
    short* Wvb  = (short*)(ws + 60817408);         // 2.1 MB
    short* Kbb  = (short*)(ws + 58720256);         // alias Wkb+Wvb after gemms
    float* Qf   = (float*)d_out;                   // fp32 Q scratch (dead after ropeQ)

    const int M = BSZ * SEQ;
    dim3 blk(256);

    int nx4 = BSZ * SEQ * DIM / 4;
    f2bf<<<dim3(nx4 / 256), blk, 0, stream>>>(X, Xb, nx4);
    int nw4 = DIM * DIM / 4;
    f2bf<<<dim3(nw4 / 256), blk, 0, stream>>>(Wq, Wqob, nw4);
    gemm_bf16<<<dim3(DIM / 128, M / 128), blk, 0, stream>>>(Xb, Wqob, Qf, M, DIM, DIM);

    int nk4 = KVDIM * DIM / 4;
    f2bf<<<dim3(nk4 / 256), blk, 0, stream>>>(Wk, Wkb, nk4);
    gemm_bf16<<<dim3(KVDIM / 128, M / 128), blk, 0, stream>>>(Xb, Wkb, Kf, M, KVDIM, DIM);
    f2bf<<<dim3(nk4 / 256), blk, 0, stream>>>(Wv, Wvb, nk4);
    gemm_bf16<<<dim3(KVDIM / 128, M / 128), blk, 0, stream>>>(Xb, Wvb, Vf, M, KVDIM, DIM);

    int tk = BSZ * SEQ * NKV * 8;
    rope_bf16<<<dim3(tk / 256), blk, 0, stream>>>(Kf, Kbb, cosT, sinT, NKV, 1.0f, tk);
    int tq = BSZ * SEQ * NH * 8;
    rope_bf16<<<dim3(tq / 256), blk, 0, stream>>>(Qf, Qbb, cosT, sinT, NH, 0.125f * 1.44269504088896f, tq);
    transv<<<dim3(SEQ / 64, BSZ * NKV), blk, 0, stream>>>(Vf, VTb);

    flash2<<<dim3(SEQ / 64, BSZ * NH), blk, 0, stream>>>(Qbb, Kbb, VTb, ATTb);

    f2bf<<<dim3(nw4 / 256), blk, 0, stream>>>(Wo, Wqob, nw4);
    gemm_bf16<<<dim3(DIM / 128, M / 128), blk, 0, stream>>>(ATTb, Wqob, (float*)d_out, M, DIM, DIM);
}

// Round 4
// 459.321 us; speedup vs baseline: 2.1458x; 2.1458x over previous
//
#include <hip/hip_runtime.h>
#include <math.h>

#define BSZ 2
#define SEQ 2048
#define DIM 2048
#define NH 32
#define NKV 8
#define HD 64
#define KVDIM 512

typedef short short8 __attribute__((ext_vector_type(8)));
typedef short short4v __attribute__((ext_vector_type(4)));
typedef float f32x4 __attribute__((ext_vector_type(4)));

__device__ __forceinline__ short fbf(float x) {
    unsigned u = __float_as_uint(x);
    u = (u + 0x7fffu + ((u >> 16) & 1u)) >> 16;   // RNE f32->bf16
    return (short)u;
}
// cheap round (half-up) for P in [0,1] — 2 VALU ops
__device__ __forceinline__ short pbf(float x) {
    return (short)((__float_as_uint(x) + 0x8000u) >> 16);
}

#define AS1(p) ((const __attribute__((address_space(1))) void*)(p))
#define AS3(p) ((__attribute__((address_space(3))) void*)(p))

// ---------------------------------------------------------------------------
// fp32 -> bf16 convert
// ---------------------------------------------------------------------------
__global__ __launch_bounds__(256) void f2bf(const float* __restrict__ in,
                                            short* __restrict__ out, int n4) {
    int i = blockIdx.x * 256 + threadIdx.x;
    if (i >= n4) return;
    float4 f = ((const float4*)in)[i];
    short4v s = { fbf(f.x), fbf(f.y), fbf(f.z), fbf(f.w) };
    ((short4v*)out)[i] = s;
}

// ---------------------------------------------------------------------------
// bf16 NT GEMM, m97-style (unchanged from round 3: 874TF-structure)
// ---------------------------------------------------------------------------
__global__ __launch_bounds__(256) void gemm_bf16(const short* __restrict__ A,
                                                 const short* __restrict__ W,
                                                 float* __restrict__ C,
                                                 int M, int N, int K) {
    __shared__ short As[128 * 64];
    __shared__ short Bs[128 * 64];
    const int tid = threadIdx.x;
    const int lane = tid & 63, wave = tid >> 6;
    const int l15 = lane & 15, quad = lane >> 4;
    const int m0 = blockIdx.y * 128, n0 = blockIdx.x * 128;
    const int wm = (wave >> 1) * 64, wn = (wave & 1) * 64;
    f32x4 acc[4][4] = {};
    int srow[4], gcol[4];
#pragma unroll
    for (int v = 0; v < 4; ++v) {
        int s = v * 256 + tid;
        srow[v] = s >> 3;
        gcol[v] = ((s & 7) ^ (srow[v] & 7)) * 8;
    }
    for (int kb = 0; kb < K; kb += 64) {
        __syncthreads();
#pragma unroll
        for (int v = 0; v < 4; ++v) {
            int s = v * 256 + tid;
            __builtin_amdgcn_global_load_lds(AS1(A + (size_t)(m0 + srow[v]) * K + kb + gcol[v]),
                                             AS3(&As[s * 8]), 16, 0, 0);
            __builtin_amdgcn_global_load_lds(AS1(W + (size_t)(n0 + srow[v]) * K + kb + gcol[v]),
                                             AS3(&Bs[s * 8]), 16, 0, 0);
        }
        __syncthreads();
#pragma unroll
        for (int kh = 0; kh < 2; ++kh) {
            const int cs = ((kh * 4 + quad) ^ (l15 & 7)) * 8;
            short8 af[4], bf8[4];
#pragma unroll
            for (int i = 0; i < 4; ++i)
                af[i] = *(const short8*)&As[(wm + i * 16 + l15) * 64 + cs];
#pragma unroll
            for (int j = 0; j < 4; ++j)
                bf8[j] = *(const short8*)&Bs[(wn + j * 16 + l15) * 64 + cs];
#pragma unroll
            for (int i = 0; i < 4; ++i)
#pragma unroll
                for (int j = 0; j < 4; ++j)
                    acc[i][j] = __builtin_amdgcn_mfma_f32_16x16x32_bf16(af[i], bf8[j], acc[i][j], 0, 0, 0);
        }
    }
#pragma unroll
    for (int i = 0; i < 4; ++i)
#pragma unroll
        for (int j = 0; j < 4; ++j)
#pragma unroll
            for (int r = 0; r < 4; ++r)
                C[(size_t)(m0 + wm + i * 16 + quad * 4 + r) * N + n0 + wn + j * 16 + l15] = acc[i][j][r];
}

// ---------------------------------------------------------------------------
// Fused RoPE + scale + fp32->bf16
// ---------------------------------------------------------------------------
__global__ __launch_bounds__(256) void rope_bf16(const float* __restrict__ X,
                                                 short* __restrict__ Y,
                                                 const float* __restrict__ cosT,
                                                 const float* __restrict__ sinT,
                                                 int heads, float scale, int total) {
    int i = blockIdx.x * 256 + threadIdx.x;
    if (i >= total) return;
    int d0 = (i & 7) * 4;
    int rh = i >> 3;
    int s = (rh / heads) & (SEQ - 1);
    const float* base = X + (size_t)rh * HD;
    float4 x1 = *(const float4*)(base + d0);
    float4 x2 = *(const float4*)(base + d0 + 32);
    float4 c1 = *(const float4*)(cosT + s * HD + d0);
    float4 s1 = *(const float4*)(sinT + s * HD + d0);
    float4 c2 = *(const float4*)(cosT + s * HD + d0 + 32);
    float4 s2 = *(const float4*)(sinT + s * HD + d0 + 32);
    short4v o1 = { fbf((x1.x * c1.x - x2.x * s1.x) * scale),
                   fbf((x1.y * c1.y - x2.y * s1.y) * scale),
                   fbf((x1.z * c1.z - x2.z * s1.z) * scale),
                   fbf((x1.w * c1.w - x2.w * s1.w) * scale) };
    short4v o2 = { fbf((x2.x * c2.x + x1.x * s2.x) * scale),
                   fbf((x2.y * c2.y + x1.y * s2.y) * scale),
                   fbf((x2.z * c2.z + x1.z * s2.z) * scale),
                   fbf((x2.w * c2.w + x1.w * s2.w) * scale) };
    *(short4v*)(Y + (size_t)rh * HD + d0) = o1;
    *(short4v*)(Y + (size_t)rh * HD + d0 + 32) = o2;
}

// ---------------------------------------------------------------------------
// V transpose + PV k-permutation: Vf [B,S,NKV,HD] fp32 -> VT [B,NKV,HD,SEQ]
// bf16 where, within each 64-aligned s-block, position i holds source
// kk(i) = 32*(i>>5) + 16*((i>>2)&1) + 4*((i>>3)&3) + (i&3).  This makes the
// flash PV B-fragments contiguous 16B reads while P's MFMA C-layout output
// feeds the A-operand directly (both operands see the same k-permutation).
// ---------------------------------------------------------------------------
__global__ __launch_bounds__(256) void transv(const float* __restrict__ Vf,
                                              short* __restrict__ VT) {
    __shared__ float T[64][65];
    const int tid = threadIdx.x;
    const int s0 = blockIdx.x * 64;
    const int bk = blockIdx.y;                 // b*NKV + kvh
    const float* src = Vf + ((size_t)(bk >> 3) * SEQ + s0) * KVDIM + (bk & 7) * HD;
#pragma unroll
    for (int v = 0; v < 4; ++v) {
        int srow = (tid >> 4) + v * 16;
        int d4 = (tid & 15) * 4;
        float4 f = *(const float4*)(src + (size_t)srow * KVDIM + d4);
        T[srow][d4 + 0] = f.x; T[srow][d4 + 1] = f.y;
        T[srow][d4 + 2] = f.z; T[srow][d4 + 3] = f.w;
    }
    __syncthreads();
    const int d = tid >> 2, sg = tid & 3;
#pragma unroll
    for (int j = 0; j < 4; ++j) {
        int ob = sg * 4 + j;                               // out 4-block 0..15
        int ss = 32 * (ob >> 3) + 16 * (ob & 1) + 4 * ((ob >> 1) & 3);
        short4v o = { fbf(T[ss + 0][d]), fbf(T[ss + 1][d]),
                      fbf(T[ss + 2][d]), fbf(T[ss + 3][d]) };
        *(short4v*)(VT + ((size_t)bk * HD + d) * SEQ + s0 + ob * 4) = o;
    }
}

// ---------------------------------------------------------------------------
// flash3: Q-tile 128 (2 row-groups of 16 per wave), KV-tile 64 staged to LDS
// via global_load_lds w16 + XOR swizzle (conflict-free b128 frags, loaded
// ONCE per block). S^T = K*Q^T puts q on l15 -> per-lane softmax stats.
// P feeds PV A-operand from registers (k-permuted VT). qt reversed so heavy
// causal blocks dispatch first.
// ---------------------------------------------------------------------------
__global__ __launch_bounds__(256, 2) void flash3(const short* __restrict__ Qb,
                                                 const short* __restrict__ Kb,
                                                 const short* __restrict__ VT,
                                                 short* __restrict__ O) {
    __shared__ short Ks[64 * 64];
    __shared__ short Vs[64 * 64];
    const int qt = (int)gridDim.x - 1 - (int)blockIdx.x;
    const int bh = blockIdx.y;
    const int b = bh >> 5, h = bh & 31, kvh = h >> 2;
    const int tid = threadIdx.x;
    const int wave = tid >> 6, lane = tid & 63;
    const int l15 = lane & 15, quad = lane >> 4;

    short8 qf[2][2];
#pragma unroll
    for (int g = 0; g < 2; ++g) {
        const short* qp = Qb + ((size_t)b * SEQ + qt * 128 + g * 64 + wave * 16 + l15) * DIM + h * HD + quad * 8;
        qf[g][0] = *(const short8*)qp;
        qf[g][1] = *(const short8*)(qp + 32);
    }
    f32x4 o[2][4] = {};
    float m[2] = {-1e30f, -1e30f}, l[2] = {0.f, 0.f};

    const short* Kbase = Kb + (size_t)b * SEQ * KVDIM + kvh * HD;
    const short* Vbase = VT + (size_t)(b * NKV + kvh) * HD * SEQ;

    int srow[2], gcol[2];
#pragma unroll
    for (int v = 0; v < 2; ++v) {
        int s = v * 256 + tid;
        srow[v] = s >> 3;
        gcol[v] = ((s & 7) ^ (srow[v] & 7)) * 8;
    }

    const int nkt = 2 * qt + 2;
    for (int kt = 0; kt < nkt; ++kt) {
        __syncthreads();
#pragma unroll
        for (int v = 0; v < 2; ++v) {
            int s = v * 256 + tid;
            __builtin_amdgcn_global_load_lds(AS1(Kbase + (size_t)(kt * 64 + srow[v]) * KVDIM + gcol[v]),
                                             AS3(&Ks[s * 8]), 16, 0, 0);
            __builtin_amdgcn_global_load_lds(AS1(Vbase + (size_t)srow[v] * SEQ + kt * 64 + gcol[v]),
                                             AS3(&Vs[s * 8]), 16, 0, 0);
        }
        __syncthreads();
        short8 vf[4][2];
#pragma unroll
        for (int dt = 0; dt < 4; ++dt)
#pragma unroll
            for (int hh = 0; hh < 2; ++hh)
                vf[dt][hh] = *(const short8*)&Vs[(dt * 16 + l15) * 64 + (((hh * 4 + quad) ^ (l15 & 7)) << 3)];

#pragma unroll
        for (int g = 0; g < 2; ++g) {
            const int qmin = qt * 128 + g * 64 + wave * 16;
            if (kt * 64 > qmin + 15) continue;    // group fully above diagonal
            f32x4 st[4] = {};
#pragma unroll
            for (int nt = 0; nt < 4; ++nt) {
                short8 ka = *(const short8*)&Ks[(nt * 16 + l15) * 64 + ((quad ^ (l15 & 7)) << 3)];
                st[nt] = __builtin_amdgcn_mfma_f32_16x16x32_bf16(ka, qf[g][0], st[nt], 0, 0, 0);
            }
#pragma unroll
            for (int nt = 0; nt < 4; ++nt) {
                short8 kb = *(const short8*)&Ks[(nt * 16 + l15) * 64 + (((4 + quad) ^ (l15 & 7)) << 3)];
                st[nt] = __builtin_amdgcn_mfma_f32_16x16x32_bf16(kb, qf[g][1], st[nt], 0, 0, 0);
            }
            if (kt * 64 + 63 > qmin) {            // diagonal tile: mask
                const int q = qmin + l15;
#pragma unroll
                for (int nt = 0; nt < 4; ++nt)
#pragma unroll
                    for (int r = 0; r < 4; ++r)
                        if (kt * 64 + nt * 16 + quad * 4 + r > q) st[nt][r] = -1e30f;
            }
            // online softmax (exp2 domain), stats per lane (q = l15)
            float mx = st[0][0];
#pragma unroll
            for (int nt = 0; nt < 4; ++nt)
#pragma unroll
                for (int r = 0; r < 4; ++r) mx = fmaxf(mx, st[nt][r]);
            mx = fmaxf(mx, __shfl_xor(mx, 16));
            mx = fmaxf(mx, __shfl_xor(mx, 32));
            float mn = fmaxf(m[g], mx);
            float al = exp2f(m[g] - mn);
            m[g] = mn;
            float p[4][4];
            float rs = 0.f;
#pragma unroll
            for (int nt = 0; nt < 4; ++nt)
#pragma unroll
                for (int r = 0; r < 4; ++r) {
                    p[nt][r] = exp2f(st[nt][r] - mn);
                    rs += p[nt][r];
                }
            rs += __shfl_xor(rs, 16);
            rs += __shfl_xor(rs, 32);
            l[g] = l[g] * al + rs;
            short8 af0, af1;                      // P -> A-frag (k-permuted)
#pragma unroll
            for (int r = 0; r < 4; ++r) {
                af0[r] = pbf(p[0][r]); af0[r + 4] = pbf(p[1][r]);
                af1[r] = pbf(p[2][r]); af1[r + 4] = pbf(p[3][r]);
            }
            float alr[4];
#pragma unroll
            for (int r = 0; r < 4; ++r) alr[r] = __shfl(al, quad * 4 + r);
#pragma unroll
            for (int dt = 0; dt < 4; ++dt) {
                f32x4 t = o[g][dt];
                t[0] *= alr[0]; t[1] *= alr[1]; t[2] *= alr[2]; t[3] *= alr[3];
                t = __builtin_amdgcn_mfma_f32_16x16x32_bf16(af0, vf[dt][0], t, 0, 0, 0);
                t = __builtin_amdgcn_mfma_f32_16x16x32_bf16(af1, vf[dt][1], t, 0, 0, 0);
                o[g][dt] = t;
            }
        }
    }
#pragma unroll
    for (int g = 0; g < 2; ++g) {
        float lr[4];
#pragma unroll
        for (int r = 0; r < 4; ++r) lr[r] = 1.0f / __shfl(l[g], quad * 4 + r);
        short* Oo = O + ((size_t)b * SEQ + qt * 128 + g * 64 + wave * 16 + quad * 4) * DIM + h * HD + l15;
#pragma unroll
        for (int r = 0; r < 4; ++r)
#pragma unroll
            for (int dt = 0; dt < 4; ++dt)
                Oo[(size_t)r * DIM + dt * 16] = fbf(o[g][dt][r] * lr[r]);
    }
}

// ---------------------------------------------------------------------------
extern "C" void kernel_launch(void* const* d_in, const int* in_sizes, int n_in,
                              void* d_out, int out_size, void* d_ws, size_t ws_size,
                              hipStream_t stream) {
    const float* X    = (const float*)d_in[0];
    const float* cosT = (const float*)d_in[2];
    const float* sinT = (const float*)d_in[3];
    const float* Wq   = (const float*)d_in[4];
    const float* Wk   = (const float*)d_in[5];
    const float* Wv   = (const float*)d_in[6];
    const float* Wo   = (const float*)d_in[7];

    char* ws = (char*)d_ws;
    float* Kf   = (float*)(ws);                    // 8.4 MB fp32 K pre-rope
    float* Vf   = (float*)(ws + 8388608);          // 8.4 MB fp32 V
    short* Xb   = (short*)(ws + 16777216);         // bf16 X; Qb aliases after X dead
    short* Qbb  = Xb;
    short* ATTb = (short*)(ws + 33554432);         // bf16 attn out
    short* Wqob = (short*)(ws + 50331648);         // bf16 Wq, later Wo
    short* VTb  = (short*)(ws + 50331648);         // alias: live gemmQ..flash only
    short* Wkb  = (short*)(ws + 58720256);
    short* Wvb  = (short*)(ws + 60817408);
    short* Kbb  = (short*)(ws + 58720256);         // alias Wkb+Wvb after gemms
    float* Qf   = (float*)d_out;                   // fp32 Q scratch (dead after ropeQ)

    const int M = BSZ * SEQ;
    dim3 blk(256);

    int nx4 = BSZ * SEQ * DIM / 4;
    f2bf<<<dim3(nx4 / 256), blk, 0, stream>>>(X, Xb, nx4);
    int nw4 = DIM * DIM / 4;
    f2bf<<<dim3(nw4 / 256), blk, 0, stream>>>(Wq, Wqob, nw4);
    gemm_bf16<<<dim3(DIM / 128, M / 128), blk, 0, stream>>>(Xb, Wqob, Qf, M, DIM, DIM);

    int nk4 = KVDIM * DIM / 4;
    f2bf<<<dim3(nk4 / 256), blk, 0, stream>>>(Wk, Wkb, nk4);
    gemm_bf16<<<dim3(KVDIM / 128, M / 128), blk, 0, stream>>>(Xb, Wkb, Kf, M, KVDIM, DIM);
    f2bf<<<dim3(nk4 / 256), blk, 0, stream>>>(Wv, Wvb, nk4);
    gemm_bf16<<<dim3(KVDIM / 128, M / 128), blk, 0, stream>>>(Xb, Wvb, Vf, M, KVDIM, DIM);

    int tk = BSZ * SEQ * NKV * 8;
    rope_bf16<<<dim3(tk / 256), blk, 0, stream>>>(Kf, Kbb, cosT, sinT, NKV, 1.0f, tk);
    int tq = BSZ * SEQ * NH * 8;
    rope_bf16<<<dim3(tq / 256), blk, 0, stream>>>(Qf, Qbb, cosT, sinT, NH, 0.125f * 1.44269504088896f, tq);
    transv<<<dim3(SEQ / 64, BSZ * NKV), blk, 0, stream>>>(Vf, VTb);

    flash3<<<dim3(SEQ / 128, BSZ * NH), blk, 0, stream>>>(Qbb, Kbb, VTb, ATTb);

    f2bf<<<dim3(nw4 / 256), blk, 0, stream>>>(Wo, Wqob, nw4);
    gemm_bf16<<<dim3(DIM / 128, M / 128), blk, 0, stream>>>(ATTb, Wqob, (float*)d_out, M, DIM, DIM);
}

// Round 6
// 360.041 us; speedup vs baseline: 2.7375x; 1.2757x over previous
//
#include <hip/hip_runtime.h>
#include <math.h>

#define BSZ 2
#define SEQ 2048
#define DIM 2048
#define NH 32
#define NKV 8
#define HD 64
#define KVDIM 512

typedef short short8 __attribute__((ext_vector_type(8)));
typedef short short4v __attribute__((ext_vector_type(4)));
typedef float f32x4 __attribute__((ext_vector_type(4)));

__device__ __forceinline__ short fbf(float x) {
    unsigned u = __float_as_uint(x);
    u = (u + 0x7fffu + ((u >> 16) & 1u)) >> 16;   // RNE f32->bf16
    return (short)u;
}
// cheap round (half-up) for P in [0,1]
__device__ __forceinline__ short pbf(float x) {
    return (short)((__float_as_uint(x) + 0x8000u) >> 16);
}

#define AS1(p) ((const __attribute__((address_space(1))) void*)(p))
#define AS3(p) ((__attribute__((address_space(3))) void*)(p))

// ---------------------------------------------------------------------------
// prep: all fp32->bf16 conversions in ONE kernel (flat float4 ranges, all
// range boundaries are multiples of 256 so blocks are branch-uniform).
// ---------------------------------------------------------------------------
__global__ __launch_bounds__(256) void prep(const float* __restrict__ X,
                                            const float* __restrict__ Wq,
                                            const float* __restrict__ Wk,
                                            const float* __restrict__ Wv,
                                            const float* __restrict__ Wo,
                                            short* __restrict__ Xb,
                                            short* __restrict__ Wqkv,
                                            short* __restrict__ Wob) {
    int i = blockIdx.x * 256 + threadIdx.x;
    const float* src; short* dst; int j;
    if (i < 2097152)      { src = X;  dst = Xb;             j = i; }
    else if (i < 3145728) { src = Wq; dst = Wqkv;           j = i - 2097152; }
    else if (i < 3407872) { src = Wk; dst = Wqkv + 4194304; j = i - 3145728; }
    else if (i < 3670016) { src = Wv; dst = Wqkv + 5242880; j = i - 3407872; }
    else                  { src = Wo; dst = Wob;            j = i - 3670016; }
    float4 f = ((const float4*)src)[j];
    short4v s = { fbf(f.x), fbf(f.y), fbf(f.z), fbf(f.w) };
    ((short4v*)dst)[j] = s;
}

// ---------------------------------------------------------------------------
// Fused QKV GEMM: C = Xb * Wqkv^T  (M=4096, N=3072, K=2048), m97-style
// K-loop. Epilogue (region is wave-uniform; boundaries multiples of 64):
//   cols [0,2048):    RoPE + qscale -> Qo bf16 [B,S,32,64]
//   cols [2048,2560): RoPE          -> Ko bf16 [B,S,8,64]
//   cols [2560,3072): transpose + PV k-permutation -> Vo bf16 [B,8,64,2048]
// ---------------------------------------------------------------------------
__global__ __launch_bounds__(256) void gemm_qkv(const short* __restrict__ A,
                                                const short* __restrict__ W,
                                                const float* __restrict__ cosT,
                                                const float* __restrict__ sinT,
                                                short* __restrict__ Qo,
                                                short* __restrict__ Ko,
                                                short* __restrict__ Vo) {
    __shared__ short As[128 * 64];
    __shared__ short Bs[128 * 64];
    const int K = 2048;
    const int tid = threadIdx.x;
    const int lane = tid & 63, wave = tid >> 6;
    const int l15 = lane & 15, quad = lane >> 4;
    const int m0 = blockIdx.y * 128, n0 = blockIdx.x * 128;
    const int wm = (wave >> 1) * 64, wn = (wave & 1) * 64;
    f32x4 acc[4][4] = {};
    int srow[4], gcol[4];
#pragma unroll
    for (int v = 0; v < 4; ++v) {
        int s = v * 256 + tid;
        srow[v] = s >> 3;
        gcol[v] = ((s & 7) ^ (srow[v] & 7)) * 8;
    }
    for (int kb = 0; kb < K; kb += 64) {
        __syncthreads();
#pragma unroll
        for (int v = 0; v < 4; ++v) {
            int s = v * 256 + tid;
            __builtin_amdgcn_global_load_lds(AS1(A + (size_t)(m0 + srow[v]) * K + kb + gcol[v]),
                                             AS3(&As[s * 8]), 16, 0, 0);
            __builtin_amdgcn_global_load_lds(AS1(W + (size_t)(n0 + srow[v]) * K + kb + gcol[v]),
                                             AS3(&Bs[s * 8]), 16, 0, 0);
        }
        __syncthreads();
#pragma unroll
        for (int kh = 0; kh < 2; ++kh) {
            const int cs = ((kh * 4 + quad) ^ (l15 & 7)) * 8;
            short8 af[4], bf8[4];
#pragma unroll
            for (int i = 0; i < 4; ++i)
                af[i] = *(const short8*)&As[(wm + i * 16 + l15) * 64 + cs];
#pragma unroll
            for (int j = 0; j < 4; ++j)
                bf8[j] = *(const short8*)&Bs[(wn + j * 16 + l15) * 64 + cs];
#pragma unroll
            for (int i = 0; i < 4; ++i)
#pragma unroll
                for (int j = 0; j < 4; ++j)
                    acc[i][j] = __builtin_amdgcn_mfma_f32_16x16x32_bf16(af[i], bf8[j], acc[i][j], 0, 0, 0);
        }
    }
    const int n0r = n0 + wn;
    if (n0r < 2560) {                         // Q or K: RoPE + store
        short* dst; int heads, hh; float scale;
        if (n0r < 2048) { dst = Qo; heads = NH;  hh = n0r >> 6;          scale = 0.125f * 1.44269504088896f; }
        else            { dst = Ko; heads = NKV; hh = (n0r - 2048) >> 6; scale = 1.0f; }
#pragma unroll
        for (int i = 0; i < 4; ++i)
#pragma unroll
            for (int r = 0; r < 4; ++r) {
                int mrow = m0 + wm + i * 16 + quad * 4 + r;
                int s = mrow & (SEQ - 1);
                int bb = mrow >> 11;
                size_t rowbase = ((size_t)(bb * SEQ + s) * heads + hh) * HD;
#pragma unroll
                for (int jp = 0; jp < 2; ++jp) {
                    int d1 = jp * 16 + l15;
                    float c1 = cosT[s * HD + d1],      s1 = sinT[s * HD + d1];
                    float c2 = cosT[s * HD + d1 + 32], s2 = sinT[s * HD + d1 + 32];
                    float x1 = acc[i][jp][r], x2 = acc[i][jp + 2][r];
                    dst[rowbase + d1]      = fbf((x1 * c1 - x2 * s1) * scale);
                    dst[rowbase + d1 + 32] = fbf((x2 * c2 + x1 * s2) * scale);
                }
            }
    } else {                                  // V: transposed + k-permuted
        const int hh = (n0r - 2560) >> 6;
#pragma unroll
        for (int i = 0; i < 4; ++i) {
            int mrow4 = m0 + wm + i * 16 + quad * 4;
            int s_abs = mrow4 & (SEQ - 1);
            int bb = mrow4 >> 11;
            int blk = s_abs >> 6, kk = s_abs & 63;   // kk multiple of 4
            int ob = ((kk >> 5) << 3) | (((kk >> 2) & 3) << 1) | ((kk >> 4) & 1);
#pragma unroll
            for (int j = 0; j < 4; ++j) {
                int d = j * 16 + l15;
                short4v pk = { fbf(acc[i][j][0]), fbf(acc[i][j][1]),
                               fbf(acc[i][j][2]), fbf(acc[i][j][3]) };
                *(short4v*)&Vo[(((size_t)(bb * NKV + hh) * HD + d) * SEQ) + blk * 64 + ob * 4] = pk;
            }
        }
    }
}

// ---------------------------------------------------------------------------
// bf16 NT GEMM (m97-style), fp32 C out — used for the Wo projection.
// ---------------------------------------------------------------------------
__global__ __launch_bounds__(256) void gemm_bf16(const short* __restrict__ A,
                                                 const short* __restrict__ W,
                                                 float* __restrict__ C,
                                                 int M, int N, int K) {
    __shared__ short As[128 * 64];
    __shared__ short Bs[128 * 64];
    const int tid = threadIdx.x;
    const int lane = tid & 63, wave = tid >> 6;
    const int l15 = lane & 15, quad = lane >> 4;
    const int m0 = blockIdx.y * 128, n0 = blockIdx.x * 128;
    const int wm = (wave >> 1) * 64, wn = (wave & 1) * 64;
    f32x4 acc[4][4] = {};
    int srow[4], gcol[4];
#pragma unroll
    for (int v = 0; v < 4; ++v) {
        int s = v * 256 + tid;
        srow[v] = s >> 3;
        gcol[v] = ((s & 7) ^ (srow[v] & 7)) * 8;
    }
    for (int kb = 0; kb < K; kb += 64) {
        __syncthreads();
#pragma unroll
        for (int v = 0; v < 4; ++v) {
            int s = v * 256 + tid;
            __builtin_amdgcn_global_load_lds(AS1(A + (size_t)(m0 + srow[v]) * K + kb + gcol[v]),
                                             AS3(&As[s * 8]), 16, 0, 0);
            __builtin_amdgcn_global_load_lds(AS1(W + (size_t)(n0 + srow[v]) * K + kb + gcol[v]),
                                             AS3(&Bs[s * 8]), 16, 0, 0);
        }
        __syncthreads();
#pragma unroll
        for (int kh = 0; kh < 2; ++kh) {
            const int cs = ((kh * 4 + quad) ^ (l15 & 7)) * 8;
            short8 af[4], bf8[4];
#pragma unroll
            for (int i = 0; i < 4; ++i)
                af[i] = *(const short8*)&As[(wm + i * 16 + l15) * 64 + cs];
#pragma unroll
            for (int j = 0; j < 4; ++j)
                bf8[j] = *(const short8*)&Bs[(wn + j * 16 + l15) * 64 + cs];
#pragma unroll
            for (int i = 0; i < 4; ++i)
#pragma unroll
                for (int j = 0; j < 4; ++j)
                    acc[i][j] = __builtin_amdgcn_mfma_f32_16x16x32_bf16(af[i], bf8[j], acc[i][j], 0, 0, 0);
        }
    }
#pragma unroll
    for (int i = 0; i < 4; ++i)
#pragma unroll
        for (int j = 0; j < 4; ++j)
#pragma unroll
            for (int r = 0; r < 4; ++r)
                C[(size_t)(m0 + wm + i * 16 + quad * 4 + r) * N + n0 + wn + j * 16 + l15] = acc[i][j][r];
}

// ---------------------------------------------------------------------------
// flash3 + double-buffered LDS prefetch + 4 blocks/CU. Grid: x = bh (64),
// y = reversed qt (16) so co-resident blocks mix heavy/light causal loads.
// ---------------------------------------------------------------------------
__global__ __launch_bounds__(256, 4) void flash3(const short* __restrict__ Qb,
                                                 const short* __restrict__ Kb,
                                                 const short* __restrict__ VT,
                                                 short* __restrict__ O) {
    __shared__ short Ks[2][64 * 64];
    __shared__ short Vs[2][64 * 64];
    const int bh = blockIdx.x;
    const int qt = (int)gridDim.y - 1 - (int)blockIdx.y;
    const int b = bh >> 5, h = bh & 31, kvh = h >> 2;
    const int tid = threadIdx.x;
    const int wave = tid >> 6, lane = tid & 63;
    const int l15 = lane & 15, quad = lane >> 4;

    short8 qf[2][2];
#pragma unroll
    for (int g = 0; g < 2; ++g) {
        const short* qp = Qb + ((size_t)b * SEQ + qt * 128 + g * 64 + wave * 16 + l15) * DIM + h * HD + quad * 8;
        qf[g][0] = *(const short8*)qp;
        qf[g][1] = *(const short8*)(qp + 32);
    }
    f32x4 o[2][4] = {};
    float m[2] = {-1e30f, -1e30f}, l[2] = {0.f, 0.f};

    const short* Kbase = Kb + (size_t)b * SEQ * KVDIM + kvh * HD;
    const short* Vbase = VT + (size_t)(b * NKV + kvh) * HD * SEQ;

    int srow[2], gcol[2];
#pragma unroll
    for (int v = 0; v < 2; ++v) {
        int s = v * 256 + tid;
        srow[v] = s >> 3;
        gcol[v] = ((s & 7) ^ (srow[v] & 7)) * 8;
    }
    auto issue = [&](int kt, int bi) {
#pragma unroll
        for (int v = 0; v < 2; ++v) {
            int s = v * 256 + tid;
            __builtin_amdgcn_global_load_lds(AS1(Kbase + (size_t)(kt * 64 + srow[v]) * KVDIM + gcol[v]),
                                             AS3(&Ks[bi][s * 8]), 16, 0, 0);
            __builtin_amdgcn_global_load_lds(AS1(Vbase + (size_t)srow[v] * SEQ + kt * 64 + gcol[v]),
                                             AS3(&Vs[bi][s * 8]), 16, 0, 0);
        }
    };
    issue(0, 0);
    const int nkt = 2 * qt + 2;
    for (int kt = 0; kt < nkt; ++kt) {
        const int bi = kt & 1;
        __syncthreads();                        // drains prefetch for kt; prev compute done
        if (kt + 1 < nkt) issue(kt + 1, bi ^ 1);
        short8 vf[4][2];
#pragma unroll
        for (int dt = 0; dt < 4; ++dt)
#pragma unroll
            for (int hh = 0; hh < 2; ++hh)
                vf[dt][hh] = *(const short8*)&Vs[bi][(dt * 16 + l15) * 64 + (((hh * 4 + quad) ^ (l15 & 7)) << 3)];

#pragma unroll
        for (int g = 0; g < 2; ++g) {
            const int qmin = qt * 128 + g * 64 + wave * 16;
            if (kt * 64 > qmin + 15) continue;    // group fully above diagonal
            f32x4 st[4] = {};
#pragma unroll
            for (int nt = 0; nt < 4; ++nt) {
                short8 ka = *(const short8*)&Ks[bi][(nt * 16 + l15) * 64 + ((quad ^ (l15 & 7)) << 3)];
                st[nt] = __builtin_amdgcn_mfma_f32_16x16x32_bf16(ka, qf[g][0], st[nt], 0, 0, 0);
            }
#pragma unroll
            for (int nt = 0; nt < 4; ++nt) {
                short8 kb = *(const short8*)&Ks[bi][(nt * 16 + l15) * 64 + (((4 + quad) ^ (l15 & 7)) << 3)];
                st[nt] = __builtin_amdgcn_mfma_f32_16x16x32_bf16(kb, qf[g][1], st[nt], 0, 0, 0);
            }
            if (kt * 64 + 63 > qmin) {            // diagonal tile: mask
                const int q = qmin + l15;
#pragma unroll
                for (int nt = 0; nt < 4; ++nt)
#pragma unroll
                    for (int r = 0; r < 4; ++r)
                        if (kt * 64 + nt * 16 + quad * 4 + r > q) st[nt][r] = -1e30f;
            }
            float mx = st[0][0];
#pragma unroll
            for (int nt = 0; nt < 4; ++nt)
#pragma unroll
                for (int r = 0; r < 4; ++r) mx = fmaxf(mx, st[nt][r]);
            mx = fmaxf(mx, __shfl_xor(mx, 16));
            mx = fmaxf(mx, __shfl_xor(mx, 32));
            float mn = fmaxf(m[g], mx);
            float al = exp2f(m[g] - mn);
            m[g] = mn;
            float p[4][4];
            float rs = 0.f;
#pragma unroll
            for (int nt = 0; nt < 4; ++nt)
#pragma unroll
                for (int r = 0; r < 4; ++r) {
                    p[nt][r] = exp2f(st[nt][r] - mn);
                    rs += p[nt][r];
                }
            rs += __shfl_xor(rs, 16);
            rs += __shfl_xor(rs, 32);
            l[g] = l[g] * al + rs;
            short8 af0, af1;                      // P -> A-frag (k-permuted)
#pragma unroll
            for (int r = 0; r < 4; ++r) {
                af0[r] = pbf(p[0][r]); af0[r + 4] = pbf(p[1][r]);
                af1[r] = pbf(p[2][r]); af1[r + 4] = pbf(p[3][r]);
            }
            float alr[4];
#pragma unroll
            for (int r = 0; r < 4; ++r) alr[r] = __shfl(al, quad * 4 + r);
#pragma unroll
            for (int dt = 0; dt < 4; ++dt) {
                f32x4 t = o[g][dt];
                t[0] *= alr[0]; t[1] *= alr[1]; t[2] *= alr[2]; t[3] *= alr[3];
                t = __builtin_amdgcn_mfma_f32_16x16x32_bf16(af0, vf[dt][0], t, 0, 0, 0);
                t = __builtin_amdgcn_mfma_f32_16x16x32_bf16(af1, vf[dt][1], t, 0, 0, 0);
                o[g][dt] = t;
            }
        }
    }
#pragma unroll
    for (int g = 0; g < 2; ++g) {
        float lr[4];
#pragma unroll
        for (int r = 0; r < 4; ++r) lr[r] = 1.0f / __shfl(l[g], quad * 4 + r);
        short* Oo = O + ((size_t)b * SEQ + qt * 128 + g * 64 + wave * 16 + quad * 4) * DIM + h * HD + l15;
#pragma unroll
        for (int r = 0; r < 4; ++r)
#pragma unroll
            for (int dt = 0; dt < 4; ++dt)
                Oo[(size_t)r * DIM + dt * 16] = fbf(o[g][dt][r] * lr[r]);
    }
}

// ---------------------------------------------------------------------------
extern "C" void kernel_launch(void* const* d_in, const int* in_sizes, int n_in,
                              void* d_out, int out_size, void* d_ws, size_t ws_size,
                              hipStream_t stream) {
    const float* X    = (const float*)d_in[0];
    const float* cosT = (const float*)d_in[2];
    const float* sinT = (const float*)d_in[3];
    const float* Wq   = (const float*)d_in[4];
    const float* Wk   = (const float*)d_in[5];
    const float* Wv   = (const float*)d_in[6];
    const float* Wo   = (const float*)d_in[7];

    char* ws = (char*)d_ws;
    short* Xb    = (short*)(ws);                  // 16.8 MB; ATTb aliases after QKV gemm
    short* ATTb  = Xb;
    short* WQKVb = (short*)(ws + 16777216);       // 12.6 MB
    short* Wob   = (short*)(ws + 29360128);       // 8.4 MB
    short* Qbb   = (short*)(ws + 37748736);       // 16.8 MB
    short* Kbb   = (short*)(ws + 54525952);       // 4.2 MB (B*S*KVDIM bf16)
    short* VTb   = (short*)(ws + 58720256);       // 4.2 MB (B*NKV*HD*SEQ bf16) -> total 62.9 MB

    const int M = BSZ * SEQ;
    dim3 blk(256);

    prep<<<dim3(18432), blk, 0, stream>>>(X, Wq, Wk, Wv, Wo, Xb, WQKVb, Wob);
    gemm_qkv<<<dim3(24, M / 128), blk, 0, stream>>>(Xb, WQKVb, cosT, sinT, Qbb, Kbb, VTb);
    flash3<<<dim3(BSZ * NH, SEQ / 128), blk, 0, stream>>>(Qbb, Kbb, VTb, ATTb);
    gemm_bf16<<<dim3(DIM / 128, M / 128), blk, 0, stream>>>(ATTb, Wob, (float*)d_out, M, DIM, DIM);
}

// Round 7
// 331.165 us; speedup vs baseline: 2.9762x; 1.0872x over previous
//
#include <hip/hip_runtime.h>
#include <math.h>

#define BSZ 2
#define SEQ 2048
#define DIM 2048
#define NH 32
#define NKV 8
#define HD 64
#define KVDIM 512

typedef short short8 __attribute__((ext_vector_type(8)));
typedef short short4v __attribute__((ext_vector_type(4)));
typedef float f32x4 __attribute__((ext_vector_type(4)));

__device__ __forceinline__ short fbf(float x) {
    unsigned u = __float_as_uint(x);
    u = (u + 0x7fffu + ((u >> 16) & 1u)) >> 16;   // RNE f32->bf16
    return (short)u;
}
// cheap round (half-up) for P in [0,1]
__device__ __forceinline__ short pbf(float x) {
    return (short)((__float_as_uint(x) + 0x8000u) >> 16);
}

#define AS1(p) ((const __attribute__((address_space(1))) void*)(p))
#define AS3(p) ((__attribute__((address_space(3))) void*)(p))

// ---------------------------------------------------------------------------
// prep: all fp32->bf16 conversions in ONE kernel.
// ---------------------------------------------------------------------------
__global__ __launch_bounds__(256) void prep(const float* __restrict__ X,
                                            const float* __restrict__ Wq,
                                            const float* __restrict__ Wk,
                                            const float* __restrict__ Wv,
                                            const float* __restrict__ Wo,
                                            short* __restrict__ Xb,
                                            short* __restrict__ Wqkv,
                                            short* __restrict__ Wob) {
    int i = blockIdx.x * 256 + threadIdx.x;
    const float* src; short* dst; int j;
    if (i < 2097152)      { src = X;  dst = Xb;             j = i; }
    else if (i < 3145728) { src = Wq; dst = Wqkv;           j = i - 2097152; }
    else if (i < 3407872) { src = Wk; dst = Wqkv + 4194304; j = i - 3145728; }
    else if (i < 3670016) { src = Wv; dst = Wqkv + 5242880; j = i - 3407872; }
    else                  { src = Wo; dst = Wob;            j = i - 3670016; }
    float4 f = ((const float4*)src)[j];
    short4v s = { fbf(f.x), fbf(f.y), fbf(f.z), fbf(f.w) };
    ((short4v*)dst)[j] = s;
}

// ---------------------------------------------------------------------------
// Fused QKV GEMM: C = Xb * Wqkv^T  (M=4096, N=3072, K=2048), m97-style
// K-loop. Epilogue:
//   cols [0,2048):    RoPE+qscale -> Qo bf16 [B,S,32,64]  (LDS-coalesced)
//   cols [2048,2560): RoPE        -> Ko bf16 [B,S,8,64]   (LDS-coalesced)
//   cols [2560,3072): transpose + PV k-permutation -> Vo bf16 [B,8,64,2048]
// Uses cos[s,d+32]==cos[s,d] (tables are concat([freqs,freqs])).
// Q/K stores: rope'd tile -> per-wave LDS (XOR 8-block swizzle; b16 writes
// 2-way-free, b128 reads optimal) -> 8x16B coalesced global stores/thread.
// ---------------------------------------------------------------------------
__global__ __launch_bounds__(256) void gemm_qkv(const short* __restrict__ A,
                                                const short* __restrict__ W,
                                                const float* __restrict__ cosT,
                                                const float* __restrict__ sinT,
                                                short* __restrict__ Qo,
                                                short* __restrict__ Ko,
                                                short* __restrict__ Vo) {
    __shared__ short SM[2 * 128 * 64];
    short* As = SM;
    short* Bs = SM + 128 * 64;
    const int K = 2048;
    const int tid = threadIdx.x;
    const int lane = tid & 63, wave = tid >> 6;
    const int l15 = lane & 15, quad = lane >> 4;
    const int m0 = blockIdx.y * 128, n0 = blockIdx.x * 128;
    const int wm = (wave >> 1) * 64, wn = (wave & 1) * 64;
    f32x4 acc[4][4] = {};
    int srow[4], gcol[4];
#pragma unroll
    for (int v = 0; v < 4; ++v) {
        int s = v * 256 + tid;
        srow[v] = s >> 3;
        gcol[v] = ((s & 7) ^ (srow[v] & 7)) * 8;
    }
    for (int kb = 0; kb < K; kb += 64) {
        __syncthreads();
#pragma unroll
        for (int v = 0; v < 4; ++v) {
            int s = v * 256 + tid;
            __builtin_amdgcn_global_load_lds(AS1(A + (size_t)(m0 + srow[v]) * K + kb + gcol[v]),
                                             AS3(&As[s * 8]), 16, 0, 0);
            __builtin_amdgcn_global_load_lds(AS1(W + (size_t)(n0 + srow[v]) * K + kb + gcol[v]),
                                             AS3(&Bs[s * 8]), 16, 0, 0);
        }
        __syncthreads();
#pragma unroll
        for (int kh = 0; kh < 2; ++kh) {
            const int cs = ((kh * 4 + quad) ^ (l15 & 7)) * 8;
            short8 af[4], bf8[4];
#pragma unroll
            for (int i = 0; i < 4; ++i)
                af[i] = *(const short8*)&As[(wm + i * 16 + l15) * 64 + cs];
#pragma unroll
            for (int j = 0; j < 4; ++j)
                bf8[j] = *(const short8*)&Bs[(wn + j * 16 + l15) * 64 + cs];
#pragma unroll
            for (int i = 0; i < 4; ++i)
#pragma unroll
                for (int j = 0; j < 4; ++j)
                    acc[i][j] = __builtin_amdgcn_mfma_f32_16x16x32_bf16(af[i], bf8[j], acc[i][j], 0, 0, 0);
        }
    }
    __syncthreads();                          // LDS free for epilogue reuse
    const int n0r = n0 + wn;
    if (n0r < 2560) {                         // Q or K: RoPE -> LDS -> 16B stores
        short* dst; int heads, hh; float scale;
        if (n0r < 2048) { dst = Qo; heads = NH;  hh = n0r >> 6;          scale = 0.125f * 1.44269504088896f; }
        else            { dst = Ko; heads = NKV; hh = (n0r - 2048) >> 6; scale = 1.0f; }
        short* EB = SM + wave * 4096;         // 64 rows x 64 cols per wave
#pragma unroll
        for (int i = 0; i < 4; ++i)
#pragma unroll
            for (int r = 0; r < 4; ++r) {
                int rr = i * 16 + quad * 4 + r;
                int s = (m0 + wm + rr) & (SEQ - 1);
                int msk = ((rr >> 1) & 7) * 8;
#pragma unroll
                for (int jp = 0; jp < 2; ++jp) {
                    int d1 = jp * 16 + l15;
                    float c1 = cosT[s * HD + d1], s1v = sinT[s * HD + d1];
                    float x1 = acc[i][jp][r], x2 = acc[i][jp + 2][r];
                    EB[rr * 64 + (d1 ^ msk)]        = fbf((x1 * c1 - x2 * s1v) * scale);
                    EB[rr * 64 + ((d1 + 32) ^ msk)] = fbf((x2 * c1 + x1 * s1v) * scale);
                }
            }
#pragma unroll
        for (int t = 0; t < 8; ++t) {
            int rr = (lane >> 3) + t * 8;
            int c = lane & 7;
            short8 v8 = *(const short8*)&EB[rr * 64 + c * 8];
            int dchunk = c ^ ((rr >> 1) & 7);
            int mrow = m0 + wm + rr;
            int s = mrow & (SEQ - 1), bb = mrow >> 11;
            *(short8*)&dst[((size_t)(bb * SEQ + s) * heads + hh) * HD + dchunk * 8] = v8;
        }
    } else {                                  // V: transposed + k-permuted
        const int hh = (n0r - 2560) >> 6;
#pragma unroll
        for (int i = 0; i < 4; ++i) {
            int mrow4 = m0 + wm + i * 16 + quad * 4;
            int s_abs = mrow4 & (SEQ - 1);
            int bb = mrow4 >> 11;
            int blk = s_abs >> 6, kk = s_abs & 63;   // kk multiple of 4
            int ob = ((kk >> 5) << 3) | (((kk >> 2) & 3) << 1) | ((kk >> 4) & 1);
#pragma unroll
            for (int j = 0; j < 4; ++j) {
                int d = j * 16 + l15;
                short4v pk = { fbf(acc[i][j][0]), fbf(acc[i][j][1]),
                               fbf(acc[i][j][2]), fbf(acc[i][j][3]) };
                *(short4v*)&Vo[(((size_t)(bb * NKV + hh) * HD + d) * SEQ) + blk * 64 + ob * 4] = pk;
            }
        }
    }
}

// ---------------------------------------------------------------------------
// bf16 NT GEMM (m97-style), fp32 C out — used for the Wo projection.
// ---------------------------------------------------------------------------
__global__ __launch_bounds__(256) void gemm_bf16(const short* __restrict__ A,
                                                 const short* __restrict__ W,
                                                 float* __restrict__ C,
                                                 int M, int N, int K) {
    __shared__ short As[128 * 64];
    __shared__ short Bs[128 * 64];
    const int tid = threadIdx.x;
    const int lane = tid & 63, wave = tid >> 6;
    const int l15 = lane & 15, quad = lane >> 4;
    const int m0 = blockIdx.y * 128, n0 = blockIdx.x * 128;
    const int wm = (wave >> 1) * 64, wn = (wave & 1) * 64;
    f32x4 acc[4][4] = {};
    int srow[4], gcol[4];
#pragma unroll
    for (int v = 0; v < 4; ++v) {
        int s = v * 256 + tid;
        srow[v] = s >> 3;
        gcol[v] = ((s & 7) ^ (srow[v] & 7)) * 8;
    }
    for (int kb = 0; kb < K; kb += 64) {
        __syncthreads();
#pragma unroll
        for (int v = 0; v < 4; ++v) {
            int s = v * 256 + tid;
            __builtin_amdgcn_global_load_lds(AS1(A + (size_t)(m0 + srow[v]) * K + kb + gcol[v]),
                                             AS3(&As[s * 8]), 16, 0, 0);
            __builtin_amdgcn_global_load_lds(AS1(W + (size_t)(n0 + srow[v]) * K + kb + gcol[v]),
                                             AS3(&Bs[s * 8]), 16, 0, 0);
        }
        __syncthreads();
#pragma unroll
        for (int kh = 0; kh < 2; ++kh) {
            const int cs = ((kh * 4 + quad) ^ (l15 & 7)) * 8;
            short8 af[4], bf8[4];
#pragma unroll
            for (int i = 0; i < 4; ++i)
                af[i] = *(const short8*)&As[(wm + i * 16 + l15) * 64 + cs];
#pragma unroll
            for (int j = 0; j < 4; ++j)
                bf8[j] = *(const short8*)&Bs[(wn + j * 16 + l15) * 64 + cs];
#pragma unroll
            for (int i = 0; i < 4; ++i)
#pragma unroll
                for (int j = 0; j < 4; ++j)
                    acc[i][j] = __builtin_amdgcn_mfma_f32_16x16x32_bf16(af[i], bf8[j], acc[i][j], 0, 0, 0);
        }
    }
#pragma unroll
    for (int i = 0; i < 4; ++i)
#pragma unroll
        for (int j = 0; j < 4; ++j)
#pragma unroll
            for (int r = 0; r < 4; ++r)
                C[(size_t)(m0 + wm + i * 16 + quad * 4 + r) * N + n0 + wn + j * 16 + l15] = acc[i][j][r];
}

// ---------------------------------------------------------------------------
// flash4: BK=128 (halved per-key softmax fixed cost, 64 MFMA per barrier),
// double-buffered global_load_lds staging (64 KB LDS, 2 blocks/CU).
// S^T = K*Q^T puts q on l15 -> per-lane softmax stats; P feeds the PV
// A-operand straight from registers via the k-permutation
//   key(kh,quad,j) = 32*kh + 16*(j>>2) + 4*quad + (j&3),  kh=0..3
// matching VT's per-64-block stored permutation. Grid y = reversed qt.
// ---------------------------------------------------------------------------
__global__ __launch_bounds__(256, 2) void flash4(const short* __restrict__ Qb,
                                                 const short* __restrict__ Kb,
                                                 const short* __restrict__ VT,
                                                 short* __restrict__ O) {
    __shared__ short Ks[2][128 * 64];
    __shared__ short Vs[2][64 * 128];
    const int bh = blockIdx.x;
    const int qt = (int)gridDim.y - 1 - (int)blockIdx.y;
    const int b = bh >> 5, h = bh & 31, kvh = h >> 2;
    const int tid = threadIdx.x;
    const int wave = tid >> 6, lane = tid & 63;
    const int l15 = lane & 15, quad = lane >> 4;

    short8 qf[2][2];
#pragma unroll
    for (int g = 0; g < 2; ++g) {
        const short* qp = Qb + ((size_t)b * SEQ + qt * 128 + g * 64 + wave * 16 + l15) * DIM + h * HD + quad * 8;
        qf[g][0] = *(const short8*)qp;
        qf[g][1] = *(const short8*)(qp + 32);
    }
    f32x4 o[2][4] = {};
    float m[2] = {-1e30f, -1e30f}, l[2] = {0.f, 0.f};

    const short* Kbase = Kb + (size_t)b * SEQ * KVDIM + kvh * HD;
    const short* Vbase = VT + (size_t)(b * NKV + kvh) * HD * SEQ;

    int krow[4], kcol[4], vrow[4], vcol[4];
#pragma unroll
    for (int v = 0; v < 4; ++v) {
        int s = v * 256 + tid;
        krow[v] = s >> 3;
        kcol[v] = ((s & 7) ^ (krow[v] & 7)) * 8;
        vrow[v] = s >> 4;
        vcol[v] = ((s & 15) ^ (vrow[v] & 7)) * 8;
    }
    auto issue = [&](int kt, int bi) {
#pragma unroll
        for (int v = 0; v < 4; ++v) {
            int s = v * 256 + tid;
            __builtin_amdgcn_global_load_lds(AS1(Kbase + (size_t)(kt * 128 + krow[v]) * KVDIM + kcol[v]),
                                             AS3(&Ks[bi][s * 8]), 16, 0, 0);
            __builtin_amdgcn_global_load_lds(AS1(Vbase + (size_t)vrow[v] * SEQ + kt * 128 + vcol[v]),
                                             AS3(&Vs[bi][s * 8]), 16, 0, 0);
        }
    };
    issue(0, 0);
    const int nkt = qt + 1;
    for (int kt = 0; kt < nkt; ++kt) {
        const int bi = kt & 1;
        __syncthreads();                        // drains prefetch for kt; prev compute done
        if (kt + 1 < nkt) issue(kt + 1, bi ^ 1);

#pragma unroll
        for (int g = 0; g < 2; ++g) {
            const int qmin = qt * 128 + g * 64 + wave * 16;
            f32x4 st[8] = {};
#pragma unroll
            for (int kh = 0; kh < 2; ++kh) {
                const int cs = ((kh * 4 + quad) ^ (l15 & 7)) * 8;
#pragma unroll
                for (int nt = 0; nt < 8; ++nt) {
                    short8 ka = *(const short8*)&Ks[bi][(nt * 16 + l15) * 64 + cs];
                    st[nt] = __builtin_amdgcn_mfma_f32_16x16x32_bf16(ka, qf[g][kh], st[nt], 0, 0, 0);
                }
            }
            if (kt * 128 + 127 > qmin) {          // diagonal tile: causal mask
                const int q = qmin + l15;
#pragma unroll
                for (int nt = 0; nt < 8; ++nt)
#pragma unroll
                    for (int r = 0; r < 4; ++r)
                        if (kt * 128 + nt * 16 + quad * 4 + r > q) st[nt][r] = -1e30f;
            }
            // online softmax (exp2 domain); stats per lane (q = l15)
            float mx = st[0][0];
#pragma unroll
            for (int nt = 0; nt < 8; ++nt)
#pragma unroll
                for (int r = 0; r < 4; ++r) mx = fmaxf(mx, st[nt][r]);
            mx = fmaxf(mx, __shfl_xor(mx, 16));
            mx = fmaxf(mx, __shfl_xor(mx, 32));
            float mn = fmaxf(m[g], mx);
            float al = exp2f(m[g] - mn);
            m[g] = mn;
            float rs = 0.f;
            short8 af[4];                         // P -> A-frags (k-permuted)
#pragma unroll
            for (int nt = 0; nt < 8; ++nt)
#pragma unroll
                for (int r = 0; r < 4; ++r) {
                    float pv = exp2f(st[nt][r] - mn);
                    rs += pv;
                    af[nt >> 1][(nt & 1) * 4 + r] = pbf(pv);
                }
            rs += __shfl_xor(rs, 16);
            rs += __shfl_xor(rs, 32);
            l[g] = l[g] * al + rs;
            float alr[4];
#pragma unroll
            for (int r = 0; r < 4; ++r) alr[r] = __shfl(al, quad * 4 + r);
#pragma unroll
            for (int dt = 0; dt < 4; ++dt) {
                f32x4 t = o[g][dt];
                t[0] *= alr[0]; t[1] *= alr[1]; t[2] *= alr[2]; t[3] *= alr[3];
#pragma unroll
                for (int kh = 0; kh < 4; ++kh) {
                    const int slot = (kh * 4 + quad) ^ (l15 & 7);   // XOR flips low-3 only
                    short8 vf = *(const short8*)&Vs[bi][(dt * 16 + l15) * 128 + slot * 8];
                    t = __builtin_amdgcn_mfma_f32_16x16x32_bf16(af[kh], vf, t, 0, 0, 0);
                }
                o[g][dt] = t;
            }
        }
    }
#pragma unroll
    for (int g = 0; g < 2; ++g) {
        float lr[4];
#pragma unroll
        for (int r = 0; r < 4; ++r) lr[r] = 1.0f / __shfl(l[g], quad * 4 + r);
        short* Oo = O + ((size_t)b * SEQ + qt * 128 + g * 64 + wave * 16 + quad * 4) * DIM + h * HD + l15;
#pragma unroll
        for (int r = 0; r < 4; ++r)
#pragma unroll
            for (int dt = 0; dt < 4; ++dt)
                Oo[(size_t)r * DIM + dt * 16] = fbf(o[g][dt][r] * lr[r]);
    }
}

// ---------------------------------------------------------------------------
extern "C" void kernel_launch(void* const* d_in, const int* in_sizes, int n_in,
                              void* d_out, int out_size, void* d_ws, size_t ws_size,
                              hipStream_t stream) {
    const float* X    = (const float*)d_in[0];
    const float* cosT = (const float*)d_in[2];
    const float* sinT = (const float*)d_in[3];
    const float* Wq   = (const float*)d_in[4];
    const float* Wk   = (const float*)d_in[5];
    const float* Wv   = (const float*)d_in[6];
    const float* Wo   = (const float*)d_in[7];

    char* ws = (char*)d_ws;
    short* Xb    = (short*)(ws);                  // 16.8 MB; ATTb aliases after QKV gemm
    short* ATTb  = Xb;
    short* WQKVb = (short*)(ws + 16777216);       // 12.6 MB
    short* Wob   = (short*)(ws + 29360128);       // 8.4 MB
    short* Qbb   = (short*)(ws + 37748736);       // 16.8 MB
    short* Kbb   = (short*)(ws + 54525952);       // 4.2 MB (B*S*KVDIM bf16)
    short* VTb   = (short*)(ws + 58720256);       // 4.2 MB (B*NKV*HD*SEQ bf16)

    const int M = BSZ * SEQ;
    dim3 blk(256);

    prep<<<dim3(18432), blk, 0, stream>>>(X, Wq, Wk, Wv, Wo, Xb, WQKVb, Wob);
    gemm_qkv<<<dim3(24, M / 128), blk, 0, stream>>>(Xb, WQKVb, cosT, sinT, Qbb, Kbb, VTb);
    flash4<<<dim3(BSZ * NH, SEQ / 128), blk, 0, stream>>>(Qbb, Kbb, VTb, ATTb);
    gemm_bf16<<<dim3(DIM / 128, M / 128), blk, 0, stream>>>(ATTb, Wob, (float*)d_out, M, DIM, DIM);
}